// Round 16
// baseline (124.266 us; speedup 1.0000x reference)
//
#include <hip/hip_runtime.h>

// VQ-VAE codebook lookup:
//   z: (64, 128, 32, 32) fp32, emb: (512, 128) fp32
//   outputs (concat in d_out, fp32): z_q (8388608) | loss (1) | indices (65536)
//
// Index output validated vs NUMPY fp32 reference (scalar threshold 10.24).
// Strategy (validated r2-r15): split-bf16 MFMA argmin (3 MFMA: zh*eh + zh*el
// + zl*eh) with uint-packed keys + near-tie flags + numpy-fp32-replica fixup
// on flagged rows. z_q/loss from pre-fixup codes (error ~4e-3 << 10.24).
//
// R16 (r15: 3 waves/SIMD only — VGPR 108+48 AGPR = 160-granule; fold ~9
// VALU/elem; ~65% stall):
//  - 2 acc chains (ks parity, r12-proven) -> 32 AGPR.
//  - fold 6 VALU/elem: pd = fmaf(-2,a0,fmaf(-2,a1,sevp)); key = bfi pattern.
//  - 2048 blocks x 128 thr (2 waves per 32-row block, k-half each):
//    target 4 waves/SIMD, 8 blocks/CU -> ~50% occupancy ceiling.
// Pipeline: memset -> prep -> dist -> fixup -> fin (5 dispatches).

#define D_DIM 128
#define HW    1024
#define GAP_THR 2.5e-4f
#define FLAG_CAP 16384

typedef short short8 __attribute__((ext_vector_type(8)));
typedef float f32x16 __attribute__((ext_vector_type(16)));

union U8 { unsigned int u[4]; short8 s; uint4 q; };

__device__ __forceinline__ unsigned short f2bf(float v) {   // RNE fp32->bf16
    unsigned int u = __builtin_bit_cast(unsigned int, v);
    return (unsigned short)((u + 0x7fffu + ((u >> 16) & 1u)) >> 16);
}
__device__ __forceinline__ float bfhi(unsigned short h) {   // bf16 -> fp32
    unsigned int u = ((unsigned int)h) << 16;
    return __builtin_bit_cast(float, u);
}
__device__ __forceinline__ unsigned int umn(unsigned int a, unsigned int b) {
    return a < b ? a : b;
}
__device__ __forceinline__ unsigned int umx(unsigned int a, unsigned int b) {
    return a > b ? a : b;
}

// -------- kernel 0: fused prep: etr (all t) + esplit (t<8192) + se (t<512) --
__global__ void prep_kernel(const float* __restrict__ emb,
                            float* __restrict__ etr,
                            uint4* __restrict__ ebh, uint4* __restrict__ ebl,
                            float* __restrict__ se) {
    const int t = blockIdx.x * 256 + threadIdx.x;   // 0..65535

    // ---- etr[d][k] = emb[k][d] (transposed codebook, 256 KB) ----
    {
        const int k = t >> 7;
        const int d = t & 127;
        etr[d * 512 + k] = emb[t];
    }

    // ---- esplit: emb -> bf16 hi/lo B-fragment images [kcol][ks][lane] ----
    if (t < 8192) {
        const int lane = t & 63;
        const int ks   = (t >> 6) & 7;
        const int kcol = t >> 9;
        const int krow = kcol * 32 + (lane & 31);
        const int d0   = ks * 16 + (lane >> 5) * 8;
        const float* ep = emb + (size_t)krow * D_DIM + d0;
        float v[8];
        #pragma unroll
        for (int j = 0; j < 8; ++j) v[j] = ep[j];
        U8 hh, ll;
        #pragma unroll
        for (int p = 0; p < 4; ++p) {
            const unsigned short h0 = f2bf(v[2*p]), h1 = f2bf(v[2*p+1]);
            const unsigned short l0 = f2bf(v[2*p]   - bfhi(h0));
            const unsigned short l1 = f2bf(v[2*p+1] - bfhi(h1));
            hh.u[p] = (unsigned int)h0 | ((unsigned int)h1 << 16);
            ll.u[p] = (unsigned int)l0 | ((unsigned int)l1 << 16);
        }
        ebh[t] = hh.q;
        ebl[t] = ll.q;
    }

    // ---- se[k] = np.sum(emb[k]**2) fp32-replica (pairwise, 8 accums) ----
    if (t < 512) {
        const float* e = emb + (size_t)t * D_DIM;
        float r[8];
        #pragma unroll
        for (int j = 0; j < 8; ++j) {
            float v = e[j];
            float p = v * v;
            asm("" : "+v"(p));   // force rounded square (no fma contraction)
            r[j] = p;
        }
        for (int i = 8; i < 128; i += 8) {
            #pragma unroll
            for (int j = 0; j < 8; ++j) {
                float v = e[i + j];
                float p = v * v;
                asm("" : "+v"(p));
                r[j] += p;
            }
        }
        se[t] = ((r[0] + r[1]) + (r[2] + r[3])) + ((r[4] + r[5]) + (r[6] + r[7]));
    }
}

// ---- kernel 1: fused dist: 2-wave k-split blocks, MFMA argmin, fused z_q --
// 2048 blocks x 128 thr. Block = 32 rows; wave wk sweeps kc in [8wk, 8wk+8).
__launch_bounds__(128, 1)
__global__ void dist_kernel(const float* __restrict__ z,
                            const uint4* __restrict__ ebh,
                            const uint4* __restrict__ ebl,
                            const float* __restrict__ se_g,
                            const float* __restrict__ emb,
                            float* __restrict__ idx_out,
                            unsigned int* __restrict__ flag_cnt,
                            int* __restrict__ flag_list,
                            float* __restrict__ zq,
                            double* __restrict__ loss) {
    __shared__ unsigned int red1[2][32], red2[2][32];
    __shared__ int   li_sh[32];
    __shared__ float ept[D_DIM * 33];   // 32-row transposed emb stage (~16.9KB)
    __shared__ float lred[2];

    const int tid  = threadIdx.x;
    const int lane = tid & 63;
    const int wk   = tid >> 6;          // k-half 0..1
    const int row  = lane & 31;
    const int nblk = blockIdx.x * 32;   // block rows (one image: 1024%32==0)
    const int bimg = nblk >> 10;
    const int hw0  = nblk & 1023;

    // ---- A-frags: load z directly (strided) + split; wave 1 L1-hits -------
    short8 Ah[8], Al[8];
    {
        const float* zc = z + (size_t)bimg * (D_DIM * HW) + hw0 + row;
        #pragma unroll
        for (int ks = 0; ks < 8; ++ks) {
            const int d0 = ks * 16 + (lane >> 5) * 8;
            float v[8];
            #pragma unroll
            for (int j = 0; j < 8; ++j) v[j] = zc[(size_t)(d0 + j) * HW];
            U8 hh, ll;
            #pragma unroll
            for (int p = 0; p < 4; ++p) {
                unsigned int hwd, lwd;
                asm("v_cvt_pk_bf16_f32 %0, %1, %2" : "=v"(hwd) : "v"(v[2*p]), "v"(v[2*p+1]));
                const float xh = __builtin_bit_cast(float, hwd << 16);
                const float yh = __builtin_bit_cast(float, hwd & 0xffff0000u);
                const float xl = v[2*p]   - xh;
                const float yl = v[2*p+1] - yh;
                asm("v_cvt_pk_bf16_f32 %0, %1, %2" : "=v"(lwd) : "v"(xl), "v"(yl));
                hh.u[p] = hwd; ll.u[p] = lwd;
            }
            Ah[ks] = hh.s; Al[ks] = ll.s;
        }
    }

    unsigned int b1[16], b2[16];
    #pragma unroll
    for (int j = 0; j < 16; ++j) { b1[j] = 0xFFFFFFFFu; b2[j] = 0xFFFFFFFFu; }

    // ---- sweep this k-half's 8 columns; B direct from global (L1/L2) ------
    for (int i = 0; i < 8; ++i) {
        const int   kc   = wk * 8 + i;
        const int   kgl  = kc * 32 + row;
        const float sevp = se_g[kgl] + 0.5f;
        const uint4* pbh = ebh + kc * 512 + lane;
        const uint4* pbl = ebl + kc * 512 + lane;

        f32x16 a0, a1;   // 2 chains by ks parity (r12-proven numerics)
        #pragma unroll
        for (int j = 0; j < 16; ++j) { a0[j] = 0.f; a1[j] = 0.f; }

        #pragma unroll
        for (int ks = 0; ks < 8; ++ks) {
            U8 bh; bh.q = pbh[ks * 64];
            U8 bl; bl.q = pbl[ks * 64];
            if (ks & 1) {
                a1 = __builtin_amdgcn_mfma_f32_32x32x16_bf16(Ah[ks], bh.s, a1, 0, 0, 0);
                a1 = __builtin_amdgcn_mfma_f32_32x32x16_bf16(Ah[ks], bl.s, a1, 0, 0, 0);
                a1 = __builtin_amdgcn_mfma_f32_32x32x16_bf16(Al[ks], bh.s, a1, 0, 0, 0);
            } else {
                a0 = __builtin_amdgcn_mfma_f32_32x32x16_bf16(Ah[ks], bh.s, a0, 0, 0, 0);
                a0 = __builtin_amdgcn_mfma_f32_32x32x16_bf16(Ah[ks], bl.s, a0, 0, 0, 0);
                a0 = __builtin_amdgcn_mfma_f32_32x32x16_bf16(Al[ks], bh.s, a0, 0, 0, 0);
            }
        }

        // fold: pd = se+0.5 - 2*(a0+a1) via 2 fmaf; key = bfi(mask, pd, kgl)
        #pragma unroll
        for (int j = 0; j < 16; ++j) {
            const float pd = fmaf(-2.f, a0[j], fmaf(-2.f, a1[j], sevp));
            const unsigned int key =
                (__builtin_bit_cast(unsigned int, pd) & 0xFFFFFE00u) | (unsigned int)kgl;
            const unsigned int m = umn(key, b1[j]);
            b2[j] = umn(umx(key, b1[j]), b2[j]);
            b1[j] = m;
        }
    }

    // ---- per-wave reduce over the 32 k-lanes -------------------------------
    #pragma unroll
    for (int off = 1; off <= 16; off <<= 1) {
        #pragma unroll
        for (int j = 0; j < 16; ++j) {
            const unsigned int o1 = (unsigned int)__shfl_xor((int)b1[j], off);
            const unsigned int o2 = (unsigned int)__shfl_xor((int)b2[j], off);
            const unsigned int m  = umn(b1[j], o1);
            b2[j] = umn(umx(b1[j], o1), umn(b2[j], o2));
            b1[j] = m;
        }
    }

    if ((lane & 31) == 0) {
        const int half = lane >> 5;
        #pragma unroll
        for (int j = 0; j < 16; ++j) {
            // C/D layout (m74/m101): row = (reg&3) + 8*(reg>>2) + 4*(lane>>5)
            const int r = (j & 3) + 8 * (j >> 2) + 4 * half;
            red1[wk][r] = b1[j];
            red2[wk][r] = b2[j];
        }
    }
    __syncthreads();

    // ---- exact top-2 merge over the 2 k-halves (threads 0..31) -------------
    if (tid < 32) {
        const unsigned int v1a = red1[0][tid], v2a = red2[0][tid];
        const unsigned int v1b = red1[1][tid], v2b = red2[1][tid];
        const unsigned int m1 = umn(v1a, v1b);
        const unsigned int m2 = umn(umn(v2a, v2b), umx(v1a, v1b));
        const int n = nblk + tid;
        const int code = (int)(m1 & 511u);
        idx_out[n] = (float)code;
        li_sh[tid] = code;
        const float f1 = __builtin_bit_cast(float, m1 & 0xFFFFFE00u);
        const float f2 = __builtin_bit_cast(float, m2 & 0xFFFFFE00u);
        if (f2 - f1 < GAP_THR) {
            unsigned int p = atomicAdd(flag_cnt, 1u);
            if (p < FLAG_CAP) flag_list[p] = n;
        }
    }
    __syncthreads();   // li_sh visible

    // ---- epilogue: stage 32 emb rows -> z_q write + loss (128 thr) ---------
    {
        const int p   = tid >> 2;         // row 0..31 (4 threads per row)
        const int sub = tid & 3;
        const float* er = emb + (size_t)li_sh[p] * D_DIM + sub * 32;
        #pragma unroll
        for (int j4 = 0; j4 < 8; ++j4) {
            const float4 v = *(const float4*)(er + j4 * 4);
            const int c = sub * 32 + j4 * 4;
            ept[(c + 0) * 33 + p] = v.x;
            ept[(c + 1) * 33 + p] = v.y;
            ept[(c + 2) * 33 + p] = v.z;
            ept[(c + 3) * 33 + p] = v.w;
        }
    }
    __syncthreads();
    {
        const int p  = tid & 31;          // hw position within tile
        const int c0 = tid >> 5;          // 0..3
        const float* zb2 = z  + (size_t)bimg * (D_DIM * HW) + hw0 + p;
        float*       qb  = zq + (size_t)bimg * (D_DIM * HW) + hw0 + p;
        float lacc = 0.f;
        #pragma unroll
        for (int i = 0; i < 32; ++i) {
            const int c = c0 + i * 4;
            const float v  = ept[c * 33 + p];
            const float zv = zb2[(size_t)c * HW];
            qb[(size_t)c * HW] = v;
            const float df = v - zv;
            lacc = fmaf(df, df, lacc);
        }
        #pragma unroll
        for (int off = 32; off > 0; off >>= 1) lacc += __shfl_down(lacc, off);
        if (lane == 0) lred[wk] = lacc;
    }
    __syncthreads();
    if (tid == 0)
        atomicAdd(loss, (double)(lred[0] + lred[1]));
}

// ------- kernel 1b: numpy-fp32-replica re-argmin, ONE row per block --------
// thread k owns code k; emb read via TRANSPOSED etr[d][k] -> coalesced.
__launch_bounds__(512)
__global__ void fixup_kernel(const float* __restrict__ z,
                             const float* __restrict__ etr,
                             const unsigned int* __restrict__ flag_cnt,
                             const int* __restrict__ flag_list,
                             const float* __restrict__ se_np,
                             float* __restrict__ idx_out) {
    __shared__ float zrow[D_DIM];
    __shared__ float q[D_DIM];
    __shared__ float rsum[8];
    __shared__ float szs;
    __shared__ float rv[8];
    __shared__ int   rix[8];

    const int tid = threadIdx.x;
    unsigned int cnt = *flag_cnt;
    if (cnt > FLAG_CAP) cnt = FLAG_CAP;

    for (unsigned int f = blockIdx.x; f < cnt; f += gridDim.x) {
        const int row = flag_list[f];
        const int b   = row >> 10;
        const int hw  = row & 1023;
        __syncthreads();   // previous iteration's readers done
        if (tid < D_DIM) {
            float v = z[(size_t)b * (D_DIM * HW) + (size_t)tid * HW + hw];
            zrow[tid] = v;
            q[tid] = v * v;   // rounded via LDS store
        }
        __syncthreads();
        // numpy pairwise sum: 8 accumulators, exact per-accumulator order
        if (tid < 8) {
            float r = q[tid];
            for (int i = 8; i < 128; i += 8) r += q[i + tid];
            rsum[tid] = r;
        }
        __syncthreads();
        if (tid == 0)
            szs = ((rsum[0] + rsum[1]) + (rsum[2] + rsum[3]))
                + ((rsum[4] + rsum[5]) + (rsum[6] + rsum[7]));
        __syncthreads();
        const float sz32 = szs;

        // thread k owns code k: etr[d*512+k] is contiguous across lanes
        const int k = tid;
        double dot0 = 0.0, dot1 = 0.0;
        #pragma unroll 4
        for (int d = 0; d < D_DIM; d += 2) {
            dot0 += (double)etr[d * 512 + k]       * (double)zrow[d];
            dot1 += (double)etr[(d + 1) * 512 + k] * (double)zrow[d + 1];
        }
        const float dotf = (float)(dot0 + dot1);    // proxy for BLAS fp32 dot
        const float T    = sz32 + se_np[k];         // np: (A + B) broadcast
        float best  = T - 2.0f * dotf;              // np: ... - 2.0*matmul
        int   besti = k;

        // exact (val, idx) min-reduce: wave shfl then cross-wave via LDS
        #pragma unroll
        for (int off = 32; off > 0; off >>= 1) {
            const float ov = __shfl_down(best, off);
            const int   oi = __shfl_down(besti, off);
            if (ov < best || (ov == best && oi < besti)) { best = ov; besti = oi; }
        }
        if ((tid & 63) == 0) { rv[tid >> 6] = best; rix[tid >> 6] = besti; }
        __syncthreads();
        if (tid == 0) {
            #pragma unroll
            for (int w = 1; w < 8; ++w)
                if (rv[w] < best || (rv[w] == best && rix[w] < besti)) {
                    best = rv[w]; besti = rix[w];
                }
            idx_out[row] = (float)besti;
        }
    }
}

// ---------------- kernel 3: finalize loss ----------------------------------
__global__ void fin_kernel(const double* __restrict__ loss, float* __restrict__ out_loss) {
    // loss = (1 + 0.25) * mean((z_q - z)^2)
    *out_loss = (float)(*loss * 1.25 / 8388608.0);
}

extern "C" void kernel_launch(void* const* d_in, const int* in_sizes, int n_in,
                              void* d_out, int out_size, void* d_ws, size_t ws_size,
                              hipStream_t stream) {
    const float* z   = (const float*)d_in[0];
    const float* emb = (const float*)d_in[1];
    float* out      = (float*)d_out;
    float* zq       = out;               // 8388608 floats
    float* out_loss = out + 8388608;     // 1 float
    float* idx_f    = out + 8388609;     // 65536 floats (indices as fp32)

    char* ws = (char*)d_ws;
    unsigned int* flag_cnt = (unsigned int*)ws;          // offset 0
    double*       loss     = (double*)(ws + 8);          // 8 bytes
    float*        se       = (float*)(ws + 10240);       // 2048 bytes
    uint4*        ebh      = (uint4*)(ws + 16384);       // 131072 bytes
    uint4*        ebl      = (uint4*)(ws + 16384 + 131072);   // 131072 bytes
    int*          flag_list= (int*)(ws + 16384 + 262144);     // 65536 bytes
    float*        etr      = (float*)(ws + 16384 + 262144 + 65536); // 262144 B

    hipMemsetAsync(d_ws, 0, 16384, stream);
    prep_kernel <<<256,  256, 0, stream>>>(emb, etr, ebh, ebl, se);
    dist_kernel <<<2048, 128, 0, stream>>>(z, ebh, ebl, se, emb, idx_f,
                                           flag_cnt, flag_list, zq, loss);
    fixup_kernel<<<2048, 512, 0, stream>>>(z, etr, flag_cnt, flag_list, se, idx_f);
    fin_kernel  <<<1,    1,   0, stream>>>(loss, out_loss);
}

// Round 17
// 100.264 us; speedup vs baseline: 1.2394x; 1.2394x over previous
//
#include <hip/hip_runtime.h>

// VQ-VAE codebook lookup:
//   z: (64, 128, 32, 32) fp32, emb: (512, 128) fp32
//   outputs (concat in d_out, fp32): z_q (8388608) | loss (1) | indices (65536)
//
// Index output validated vs NUMPY fp32 reference (scalar threshold 10.24).
// Strategy (validated r2-r16): split-bf16 MFMA argmin (3 MFMA: zh*eh + zh*el
// + zl*eh) with uint-packed keys + near-tie flags + numpy-fp32-replica fixup
// on flagged rows. z_q/loss from pre-fixup codes (error ~4e-3 << 10.24).
//
// R17 (r16's 128-thr blocks regressed — per-block A-prologue/epilogue fixed
// costs doubled; r15 remains the best-measured structure at 101us total):
//  - REVERT to r15's 1024x256 (2n x 2k waves) dist.
//  - + XCD-aware blockIdx swizzle (T1; 1024%8==0 -> bijective simple form).
//  - + s_setprio(1) around the MFMA cluster (T5; r15's waves are phase-
//    diverse inside the kc loop -> scheduler has something to arbitrate).
// Pipeline: memset -> prep -> dist -> fixup -> fin (5 dispatches).

#define D_DIM 128
#define HW    1024
#define GAP_THR 2.5e-4f
#define FLAG_CAP 16384

typedef short short8 __attribute__((ext_vector_type(8)));
typedef float f32x16 __attribute__((ext_vector_type(16)));

union U8 { unsigned int u[4]; short8 s; uint4 q; };

__device__ __forceinline__ unsigned short f2bf(float v) {   // RNE fp32->bf16
    unsigned int u = __builtin_bit_cast(unsigned int, v);
    return (unsigned short)((u + 0x7fffu + ((u >> 16) & 1u)) >> 16);
}
__device__ __forceinline__ float bfhi(unsigned short h) {   // bf16 -> fp32
    unsigned int u = ((unsigned int)h) << 16;
    return __builtin_bit_cast(float, u);
}
__device__ __forceinline__ unsigned int umn(unsigned int a, unsigned int b) {
    return a < b ? a : b;
}
__device__ __forceinline__ unsigned int umx(unsigned int a, unsigned int b) {
    return a > b ? a : b;
}

// -------- kernel 0: fused prep: etr (all t) + esplit (t<8192) + se (t<512) --
__global__ void prep_kernel(const float* __restrict__ emb,
                            float* __restrict__ etr,
                            uint4* __restrict__ ebh, uint4* __restrict__ ebl,
                            float* __restrict__ se) {
    const int t = blockIdx.x * 256 + threadIdx.x;   // 0..65535

    // ---- etr[d][k] = emb[k][d] (transposed codebook, 256 KB) ----
    {
        const int k = t >> 7;
        const int d = t & 127;
        etr[d * 512 + k] = emb[t];
    }

    // ---- esplit: emb -> bf16 hi/lo B-fragment images [kcol][ks][lane] ----
    if (t < 8192) {
        const int lane = t & 63;
        const int ks   = (t >> 6) & 7;
        const int kcol = t >> 9;
        const int krow = kcol * 32 + (lane & 31);
        const int d0   = ks * 16 + (lane >> 5) * 8;
        const float* ep = emb + (size_t)krow * D_DIM + d0;
        float v[8];
        #pragma unroll
        for (int j = 0; j < 8; ++j) v[j] = ep[j];
        U8 hh, ll;
        #pragma unroll
        for (int p = 0; p < 4; ++p) {
            const unsigned short h0 = f2bf(v[2*p]), h1 = f2bf(v[2*p+1]);
            const unsigned short l0 = f2bf(v[2*p]   - bfhi(h0));
            const unsigned short l1 = f2bf(v[2*p+1] - bfhi(h1));
            hh.u[p] = (unsigned int)h0 | ((unsigned int)h1 << 16);
            ll.u[p] = (unsigned int)l0 | ((unsigned int)l1 << 16);
        }
        ebh[t] = hh.q;
        ebl[t] = ll.q;
    }

    // ---- se[k] = np.sum(emb[k]**2) fp32-replica (pairwise, 8 accums) ----
    if (t < 512) {
        const float* e = emb + (size_t)t * D_DIM;
        float r[8];
        #pragma unroll
        for (int j = 0; j < 8; ++j) {
            float v = e[j];
            float p = v * v;
            asm("" : "+v"(p));   // force rounded square (no fma contraction)
            r[j] = p;
        }
        for (int i = 8; i < 128; i += 8) {
            #pragma unroll
            for (int j = 0; j < 8; ++j) {
                float v = e[i + j];
                float p = v * v;
                asm("" : "+v"(p));
                r[j] += p;
            }
        }
        se[t] = ((r[0] + r[1]) + (r[2] + r[3])) + ((r[4] + r[5]) + (r[6] + r[7]));
    }
}

// ---- kernel 1: fused dist: 2n x 2k waves, MFMA argmin, fused z_q ----------
// 1024 blocks x 256 thr. Wave (wn,wk): rows blk*64+wn*32..+32, kc in [8wk,8wk+8).
__launch_bounds__(256, 1)
__global__ void dist_kernel(const float* __restrict__ z,
                            const uint4* __restrict__ ebh,
                            const uint4* __restrict__ ebl,
                            const float* __restrict__ se_g,
                            const float* __restrict__ emb,
                            float* __restrict__ idx_out,
                            unsigned int* __restrict__ flag_cnt,
                            int* __restrict__ flag_list,
                            float* __restrict__ zq,
                            double* __restrict__ loss) {
    __shared__ unsigned int red1[2][64], red2[2][64];
    __shared__ int   li_sh[64];
    __shared__ float ept[D_DIM * 33];   // 32-row transposed emb stage
    __shared__ float lred[4];

    const int tid  = threadIdx.x;
    const int lane = tid & 63;
    const int wid  = tid >> 6;
    const int wn   = wid >> 1;          // n-subtile 0..1
    const int wk   = wid & 1;           // k-half 0..1
    const int row  = lane & 31;
    // XCD-aware swizzle (T1): 1024 blocks, 8 XCDs, 1024%8==0 -> bijective.
    const int bidl = (int)blockIdx.x;
    const int bid  = (bidl & 7) * 128 + (bidl >> 3);
    const int nblk = bid * 64;          // block rows (one image: 1024%64==0)
    const int bimg = nblk >> 10;
    const int hw0  = nblk & 1023;
    const int hww  = hw0 + wn * 32;

    // ---- A-frags: load z directly (strided, 2x128B per instr) + split -----
    // The two k-waves with the same wn load identical addresses -> L1 hit.
    short8 Ah[8], Al[8];
    {
        const float* zc = z + (size_t)bimg * (D_DIM * HW) + hww + row;
        #pragma unroll
        for (int ks = 0; ks < 8; ++ks) {
            const int d0 = ks * 16 + (lane >> 5) * 8;
            float v[8];
            #pragma unroll
            for (int j = 0; j < 8; ++j) v[j] = zc[(size_t)(d0 + j) * HW];
            U8 hh, ll;
            #pragma unroll
            for (int p = 0; p < 4; ++p) {
                unsigned int hwd, lwd;
                asm("v_cvt_pk_bf16_f32 %0, %1, %2" : "=v"(hwd) : "v"(v[2*p]), "v"(v[2*p+1]));
                const float xh = __builtin_bit_cast(float, hwd << 16);
                const float yh = __builtin_bit_cast(float, hwd & 0xffff0000u);
                const float xl = v[2*p]   - xh;
                const float yl = v[2*p+1] - yh;
                asm("v_cvt_pk_bf16_f32 %0, %1, %2" : "=v"(lwd) : "v"(xl), "v"(yl));
                hh.u[p] = hwd; ll.u[p] = lwd;
            }
            Ah[ks] = hh.s; Al[ks] = ll.s;
        }
    }

    unsigned int b1[16], b2[16];
    #pragma unroll
    for (int j = 0; j < 16; ++j) { b1[j] = 0xFFFFFFFFu; b2[j] = 0xFFFFFFFFu; }

    // ---- sweep this k-half's 8 columns; B direct from global (L1-shared) ---
    for (int i = 0; i < 8; ++i) {
        const int   kc   = wk * 8 + i;
        const int   kgl  = kc * 32 + row;
        const float sevp = se_g[kgl] + 0.5f;
        const uint4* pbh = ebh + kc * 512 + lane;
        const uint4* pbl = ebl + kc * 512 + lane;

        f32x16 ahh, ahl, alh;   // 3 independent chains (depth 8 each)
        #pragma unroll
        for (int j = 0; j < 16; ++j) { ahh[j] = 0.f; ahl[j] = 0.f; alh[j] = 0.f; }

        __builtin_amdgcn_s_setprio(1);   // T5: favor MFMA-issuing wave
        #pragma unroll
        for (int ks = 0; ks < 8; ++ks) {
            U8 bh; bh.q = pbh[ks * 64];
            U8 bl; bl.q = pbl[ks * 64];
            ahh = __builtin_amdgcn_mfma_f32_32x32x16_bf16(Ah[ks], bh.s, ahh, 0, 0, 0);
            ahl = __builtin_amdgcn_mfma_f32_32x32x16_bf16(Ah[ks], bl.s, ahl, 0, 0, 0);
            alh = __builtin_amdgcn_mfma_f32_32x32x16_bf16(Al[ks], bh.s, alh, 0, 0, 0);
        }
        __builtin_amdgcn_s_setprio(0);

        // fold with uint-packed keys: pd = (se - 2*dot) + 0.5 in (0.25, 1)
        #pragma unroll
        for (int j = 0; j < 16; ++j) {
            const float pd = fmaf(-2.f, ahh[j],
                             fmaf(-2.f, ahl[j],
                             fmaf(-2.f, alh[j], sevp)));
            const unsigned int key =
                (__builtin_bit_cast(unsigned int, pd) & 0xFFFFFE00u) | (unsigned int)kgl;
            const unsigned int m = umn(key, b1[j]);
            b2[j] = umn(umx(key, b1[j]), b2[j]);
            b1[j] = m;
        }
    }

    // ---- per-wave reduce over the 32 k-lanes -------------------------------
    #pragma unroll
    for (int off = 1; off <= 16; off <<= 1) {
        #pragma unroll
        for (int j = 0; j < 16; ++j) {
            const unsigned int o1 = (unsigned int)__shfl_xor((int)b1[j], off);
            const unsigned int o2 = (unsigned int)__shfl_xor((int)b2[j], off);
            const unsigned int m  = umn(b1[j], o1);
            b2[j] = umn(umx(b1[j], o1), umn(b2[j], o2));
            b1[j] = m;
        }
    }

    if ((lane & 31) == 0) {
        const int half = lane >> 5;
        #pragma unroll
        for (int j = 0; j < 16; ++j) {
            // C/D layout (m74/m101): row = (reg&3) + 8*(reg>>2) + 4*(lane>>5)
            const int r = wn * 32 + (j & 3) + 8 * (j >> 2) + 4 * half;
            red1[wk][r] = b1[j];
            red2[wk][r] = b2[j];
        }
    }
    __syncthreads();

    // ---- exact top-2 merge over the 2 k-halves (threads 0..63) -------------
    if (tid < 64) {
        const unsigned int v1a = red1[0][tid], v2a = red2[0][tid];
        const unsigned int v1b = red1[1][tid], v2b = red2[1][tid];
        const unsigned int m1 = umn(v1a, v1b);
        const unsigned int m2 = umn(umn(v2a, v2b), umx(v1a, v1b));
        const int n = nblk + tid;
        const int code = (int)(m1 & 511u);
        idx_out[n] = (float)code;
        li_sh[tid] = code;
        const float f1 = __builtin_bit_cast(float, m1 & 0xFFFFFE00u);
        const float f2 = __builtin_bit_cast(float, m2 & 0xFFFFFE00u);
        if (f2 - f1 < GAP_THR) {
            unsigned int p = atomicAdd(flag_cnt, 1u);
            if (p < FLAG_CAP) flag_list[p] = n;
        }
    }

    // ---- epilogue: 2 phases x 32 rows (r12-validated stage/write) ----------
    float lacc = 0.f;
    for (int h = 0; h < 2; ++h) {
        __syncthreads();   // li_sh ready (h=0) / previous phase readers done
        {
            const int p   = tid >> 3;         // row 0..31 (8 threads per row)
            const int sub = tid & 7;
            const float* er = emb + (size_t)li_sh[h * 32 + p] * D_DIM + sub * 16;
            #pragma unroll
            for (int j4 = 0; j4 < 4; ++j4) {
                const float4 v = *(const float4*)(er + j4 * 4);
                const int c = sub * 16 + j4 * 4;
                ept[(c + 0) * 33 + p] = v.x;
                ept[(c + 1) * 33 + p] = v.y;
                ept[(c + 2) * 33 + p] = v.z;
                ept[(c + 3) * 33 + p] = v.w;
            }
        }
        __syncthreads();
        {
            const int p  = tid & 31;          // hw position within phase tile
            const int c0 = tid >> 5;          // 0..7
            const int hwp = hw0 + h * 32 + p;
            const float* zb2 = z  + (size_t)bimg * (D_DIM * HW) + hwp;
            float*       qb  = zq + (size_t)bimg * (D_DIM * HW) + hwp;
            #pragma unroll
            for (int i = 0; i < 16; ++i) {
                const int c = c0 + i * 8;
                const float v  = ept[c * 33 + p];
                const float zv = zb2[(size_t)c * HW];
                qb[(size_t)c * HW] = v;
                const float df = v - zv;
                lacc = fmaf(df, df, lacc);
            }
        }
    }
    #pragma unroll
    for (int off = 32; off > 0; off >>= 1) lacc += __shfl_down(lacc, off);
    if (lane == 0) lred[wid] = lacc;
    __syncthreads();
    if (tid == 0)
        atomicAdd(loss, (double)(lred[0] + lred[1] + lred[2] + lred[3]));
}

// ------- kernel 1b: numpy-fp32-replica re-argmin, ONE row per block --------
// thread k owns code k; emb read via TRANSPOSED etr[d][k] -> coalesced.
__launch_bounds__(512)
__global__ void fixup_kernel(const float* __restrict__ z,
                             const float* __restrict__ etr,
                             const unsigned int* __restrict__ flag_cnt,
                             const int* __restrict__ flag_list,
                             const float* __restrict__ se_np,
                             float* __restrict__ idx_out) {
    __shared__ float zrow[D_DIM];
    __shared__ float q[D_DIM];
    __shared__ float rsum[8];
    __shared__ float szs;
    __shared__ float rv[8];
    __shared__ int   rix[8];

    const int tid = threadIdx.x;
    unsigned int cnt = *flag_cnt;
    if (cnt > FLAG_CAP) cnt = FLAG_CAP;

    for (unsigned int f = blockIdx.x; f < cnt; f += gridDim.x) {
        const int row = flag_list[f];
        const int b   = row >> 10;
        const int hw  = row & 1023;
        __syncthreads();   // previous iteration's readers done
        if (tid < D_DIM) {
            float v = z[(size_t)b * (D_DIM * HW) + (size_t)tid * HW + hw];
            zrow[tid] = v;
            q[tid] = v * v;   // rounded via LDS store
        }
        __syncthreads();
        // numpy pairwise sum: 8 accumulators, exact per-accumulator order
        if (tid < 8) {
            float r = q[tid];
            for (int i = 8; i < 128; i += 8) r += q[i + tid];
            rsum[tid] = r;
        }
        __syncthreads();
        if (tid == 0)
            szs = ((rsum[0] + rsum[1]) + (rsum[2] + rsum[3]))
                + ((rsum[4] + rsum[5]) + (rsum[6] + rsum[7]));
        __syncthreads();
        const float sz32 = szs;

        // thread k owns code k: etr[d*512+k] is contiguous across lanes
        const int k = tid;
        double dot0 = 0.0, dot1 = 0.0;
        #pragma unroll 4
        for (int d = 0; d < D_DIM; d += 2) {
            dot0 += (double)etr[d * 512 + k]       * (double)zrow[d];
            dot1 += (double)etr[(d + 1) * 512 + k] * (double)zrow[d + 1];
        }
        const float dotf = (float)(dot0 + dot1);    // proxy for BLAS fp32 dot
        const float T    = sz32 + se_np[k];         // np: (A + B) broadcast
        float best  = T - 2.0f * dotf;              // np: ... - 2.0*matmul
        int   besti = k;

        // exact (val, idx) min-reduce: wave shfl then cross-wave via LDS
        #pragma unroll
        for (int off = 32; off > 0; off >>= 1) {
            const float ov = __shfl_down(best, off);
            const int   oi = __shfl_down(besti, off);
            if (ov < best || (ov == best && oi < besti)) { best = ov; besti = oi; }
        }
        if ((tid & 63) == 0) { rv[tid >> 6] = best; rix[tid >> 6] = besti; }
        __syncthreads();
        if (tid == 0) {
            #pragma unroll
            for (int w = 1; w < 8; ++w)
                if (rv[w] < best || (rv[w] == best && rix[w] < besti)) {
                    best = rv[w]; besti = rix[w];
                }
            idx_out[row] = (float)besti;
        }
    }
}

// ---------------- kernel 3: finalize loss ----------------------------------
__global__ void fin_kernel(const double* __restrict__ loss, float* __restrict__ out_loss) {
    // loss = (1 + 0.25) * mean((z_q - z)^2)
    *out_loss = (float)(*loss * 1.25 / 8388608.0);
}

extern "C" void kernel_launch(void* const* d_in, const int* in_sizes, int n_in,
                              void* d_out, int out_size, void* d_ws, size_t ws_size,
                              hipStream_t stream) {
    const float* z   = (const float*)d_in[0];
    const float* emb = (const float*)d_in[1];
    float* out      = (float*)d_out;
    float* zq       = out;               // 8388608 floats
    float* out_loss = out + 8388608;     // 1 float
    float* idx_f    = out + 8388609;     // 65536 floats (indices as fp32)

    char* ws = (char*)d_ws;
    unsigned int* flag_cnt = (unsigned int*)ws;          // offset 0
    double*       loss     = (double*)(ws + 8);          // 8 bytes
    float*        se       = (float*)(ws + 10240);       // 2048 bytes
    uint4*        ebh      = (uint4*)(ws + 16384);       // 131072 bytes
    uint4*        ebl      = (uint4*)(ws + 16384 + 131072);   // 131072 bytes
    int*          flag_list= (int*)(ws + 16384 + 262144);     // 65536 bytes
    float*        etr      = (float*)(ws + 16384 + 262144 + 65536); // 262144 B

    hipMemsetAsync(d_ws, 0, 16384, stream);
    prep_kernel <<<256,  256, 0, stream>>>(emb, etr, ebh, ebl, se);
    dist_kernel <<<1024, 256, 0, stream>>>(z, ebh, ebl, se, emb, idx_f,
                                           flag_cnt, flag_list, zq, loss);
    fixup_kernel<<<2048, 512, 0, stream>>>(z, etr, flag_cnt, flag_list, se, idx_f);
    fin_kernel  <<<1,    1,   0, stream>>>(loss, out_loss);
}